// Round 2
// baseline (692.861 us; speedup 1.0000x reference)
//
#include <hip/hip_runtime.h>

typedef unsigned short ushort_t;
typedef unsigned int uint_t;

typedef __bf16 bf16x8 __attribute__((ext_vector_type(8)));
typedef float f32x4 __attribute__((ext_vector_type(4)));

static __device__ __forceinline__ float bf2f(ushort_t h) {
    return __uint_as_float(((uint_t)h) << 16);
}
static __device__ __forceinline__ ushort_t f2bf(float f) {
    uint_t u = __float_as_uint(f);
    u = u + 0x7FFFu + ((u >> 16) & 1u);   // round-to-nearest-even
    return (ushort_t)(u >> 16);
}
// load one external float scalar, dtype chosen by runtime flag
static __device__ __forceinline__ float ldf(const void* p, size_t i, int f32m) {
    return f32m ? ((const float*)p)[i] : bf2f(((const ushort_t*)p)[i]);
}

// ---------------- constants ----------------
#define BB 32
#define HH 56
#define WW_ 56
#define CC 128
#define NHEAD 4
#define WS 7
#define SS 3
#define LL (HH * WW_)           // 3136
#define NTOK (BB * LL)          // 100352
#define NWIN (BB * 64)          // 2048
#define NN 49
#define HD 32

// token index -> windowed index (shift + window partition)
static __device__ __forceinline__ int tok2win(int t) {
    int bb = t / LL;
    int rem = t - bb * LL;
    int hh = rem / WW_;
    int ww = rem - hh * WW_;
    int ip = hh - SS; if (ip < 0) ip += HH;
    int jp = ww - SS; if (jp < 0) jp += WW_;
    int wi = ip / WS, ti = ip - wi * WS;
    int wj = jp / WS, tj = jp - wj * WS;
    return ((bb << 6) + (wi << 3) + wj) * NN + ti * WS + tj;
}

// ============ K0: dtype sniffer ============
// Examines even 16-bit words of x. bf16 data: sane exponents, nonzero.
// fp32 data: those words are mantissa bits -> extreme exponents or all zero.
__global__ __launch_bounds__(256) void sniff_kernel(const ushort_t* __restrict__ x,
                                                    int* __restrict__ flag) {
    __shared__ int cnt, zcnt;
    if (threadIdx.x == 0) { cnt = 0; zcnt = 0; }
    __syncthreads();
    int c = 0, z = 0;
    for (int i = 0; i < 16; ++i) {
        ushort_t h = x[(threadIdx.x * 16 + i) * 2];
        int e = (h >> 7) & 0xFF;
        if (e >= 0xC0 || (e < 0x40 && (h & 0x7FFFu) != 0)) c++;
        if ((h & 0x7FFFu) == 0) z++;
    }
    atomicAdd(&cnt, c);
    atomicAdd(&zcnt, z);
    __syncthreads();
    if (threadIdx.x == 0) *flag = (cnt > 64 || zcnt > 2048) ? 1 : 0;
}

// ============ K1: LN1 + cyclic shift + window partition ============
__global__ __launch_bounds__(256) void ln1_shift_window(
    const void* __restrict__ x, const void* __restrict__ g,
    const void* __restrict__ b, ushort_t* __restrict__ wbuf,
    const int* __restrict__ flag) {
    const int f32m = *flag;
    int wid = blockIdx.x * 4 + (threadIdx.x >> 6);   // windowed token id
    int lane = threadIdx.x & 63;
    int win = wid / NN, t = wid - win * NN;
    int bb = win >> 6, wrem = win & 63;
    int wi = wrem >> 3, wj = wrem & 7;
    int ti = t / WS, tj = t - ti * WS;
    int hh = wi * WS + ti + SS; if (hh >= HH) hh -= HH;
    int ww = wj * WS + tj + SS; if (ww >= WW_) ww -= WW_;
    size_t src = ((size_t)bb * LL + hh * WW_ + ww) * CC + lane * 2;
    float v0, v1;
    if (f32m) {
        float2 t2 = *(const float2*)((const float*)x + src);
        v0 = t2.x; v1 = t2.y;
    } else {
        ushort2 t2 = *(const ushort2*)((const ushort_t*)x + src);
        v0 = bf2f(t2.x); v1 = bf2f(t2.y);
    }
    float s = v0 + v1, sq = v0 * v0 + v1 * v1;
    #pragma unroll
    for (int o = 32; o > 0; o >>= 1) {
        s += __shfl_xor(s, o, 64);
        sq += __shfl_xor(sq, o, 64);
    }
    float mean = s * (1.0f / 128.0f);
    float var = sq * (1.0f / 128.0f) - mean * mean;
    float rstd = rsqrtf(var + 1e-5f);
    int c = lane * 2;
    float y0 = (v0 - mean) * rstd * ldf(g, c, f32m) + ldf(b, c, f32m);
    float y1 = (v1 - mean) * rstd * ldf(g, c + 1, f32m) + ldf(b, c + 1, f32m);
    ushort2 st; st.x = f2bf(y0); st.y = f2bf(y1);
    *(ushort2*)&wbuf[(size_t)wid * CC + c] = st;
}

// ============ K2: GEMM  out[m][n] = sum_k A[m][k]*W[n][k] + bias[n] ============
// ACT 1 = exact GELU. RESID 1 = add x[tok] + proj[tok2win(tok)] and write d_out
// in the flag-selected dtype.
template <int ACT, int RESID>
__global__ __launch_bounds__(256) void gemm_bt(
    const ushort_t* __restrict__ A, const void* __restrict__ W,
    const void* __restrict__ bias, const void* __restrict__ xin,
    const ushort_t* __restrict__ proj, void* __restrict__ out,
    int N, int K, const int* __restrict__ flag, int grow0) {
    __shared__ __align__(16) ushort_t As[64 * 128];
    __shared__ __align__(16) ushort_t Ws[64 * 128];
    const int f32m = *flag;
    const int tid = threadIdx.x;
    const int m0 = blockIdx.x * 64;
    const int n0 = blockIdx.y * 64;
    const int wave = tid >> 6;
    const int lane = tid & 63;
    const int l16 = lane & 15;
    const int quad = lane >> 4;

    f32x4 zero = {0.f, 0.f, 0.f, 0.f};
    f32x4 acc[4] = {zero, zero, zero, zero};

    for (int kc = 0; kc < K; kc += 128) {
        // stage A (always bf16 internal)
        #pragma unroll
        for (int u = tid; u < 1024; u += 256) {
            int row = u >> 4;
            int col = (u & 15) << 3;
            *(uint4*)&As[row * 128 + col] =
                *(const uint4*)&A[(size_t)(m0 + row) * K + kc + col];
        }
        // stage W (external: dtype per flag)
        if (f32m) {
            const float* Wf = (const float*)W;
            #pragma unroll
            for (int u = tid; u < 1024; u += 256) {
                int row = u >> 4;
                int col = (u & 15) << 3;
                const float* sp = &Wf[(size_t)(n0 + row) * K + kc + col];
                float4 a0 = *(const float4*)sp;
                float4 a1 = *(const float4*)(sp + 4);
                ushort_t* dp = &Ws[row * 128 + col];
                dp[0] = f2bf(a0.x); dp[1] = f2bf(a0.y);
                dp[2] = f2bf(a0.z); dp[3] = f2bf(a0.w);
                dp[4] = f2bf(a1.x); dp[5] = f2bf(a1.y);
                dp[6] = f2bf(a1.z); dp[7] = f2bf(a1.w);
            }
        } else {
            const ushort_t* Wh = (const ushort_t*)W;
            #pragma unroll
            for (int u = tid; u < 1024; u += 256) {
                int row = u >> 4;
                int col = (u & 15) << 3;
                *(uint4*)&Ws[row * 128 + col] =
                    *(const uint4*)&Wh[(size_t)(n0 + row) * K + kc + col];
            }
        }
        __syncthreads();
        #pragma unroll
        for (int kk = 0; kk < 128; kk += 32) {
            bf16x8 a = *(const bf16x8*)&As[(wave * 16 + l16) * 128 + kk + quad * 8];
            #pragma unroll
            for (int j = 0; j < 4; ++j) {
                bf16x8 bfr = *(const bf16x8*)&Ws[(j * 16 + l16) * 128 + kk + quad * 8];
                acc[j] = __builtin_amdgcn_mfma_f32_16x16x32_bf16(a, bfr, acc[j], 0, 0, 0);
            }
        }
        __syncthreads();
    }
    #pragma unroll
    for (int j = 0; j < 4; ++j) {
        int col = n0 + j * 16 + l16;
        float bv = ldf(bias, col, f32m);
        #pragma unroll
        for (int r = 0; r < 4; ++r) {
            int row = m0 + wave * 16 + quad * 4 + r;
            float val = acc[j][r] + bv;
            if (ACT == 1) val = 0.5f * val * (1.0f + erff(val * 0.70710678118654752f));
            if (RESID == 1) {
                int grow = grow0 + row;                     // global token
                int mwin = tok2win(grow);                   // windowed index
                val += ldf(xin, (size_t)grow * CC + col, f32m)
                     + bf2f(proj[(size_t)mwin * CC + col]);
                size_t oi = (size_t)grow * CC + col;
                if (f32m) ((float*)out)[oi] = val;
                else      ((ushort_t*)out)[oi] = f2bf(val);
            } else {
                ((ushort_t*)out)[(size_t)row * N + col] = f2bf(val);
            }
        }
    }
}

// ============ K3: windowed attention, one block per (window, head) ============
__global__ __launch_bounds__(256) void attn_kernel(
    const ushort_t* __restrict__ qkv, const void* __restrict__ rpb,
    const int* __restrict__ rel_idx, ushort_t* __restrict__ attn_out,
    const int* __restrict__ flag) {
    const int f32m = *flag;
    int win = blockIdx.x >> 2;      // local window within chunk
    int h = blockIdx.x & 3;
    __shared__ float q[NN * HD];
    __shared__ float k[NN * HD];
    __shared__ float v[NN * HD];
    __shared__ float s[NN * 50];
    const int tid = threadIdx.x;
    const float scale = 0.17677669529663687f;  // 32^-0.5

    for (int idx = tid; idx < NN * HD; idx += 256) {
        int i = idx >> 5, d = idx & 31;
        size_t base = ((size_t)(win * NN + i)) * 384 + h * HD + d;
        q[idx] = bf2f(qkv[base]) * scale;
        k[idx] = bf2f(qkv[base + 128]);
        v[idx] = bf2f(qkv[base + 256]);
    }
    __syncthreads();
    for (int idx = tid; idx < NN * NN; idx += 256) {
        int i = idx / NN, j = idx - i * NN;
        float acc = 0.f;
        #pragma unroll
        for (int d = 0; d < HD; ++d) acc += q[i * HD + d] * k[j * HD + d];
        acc += ldf(rpb, (size_t)rel_idx[idx] * NHEAD + h, f32m);
        s[i * 50 + j] = acc;
    }
    __syncthreads();
    if (tid < NN) {
        float m = -1e30f;
        for (int j = 0; j < NN; ++j) m = fmaxf(m, s[tid * 50 + j]);
        float sum = 0.f;
        for (int j = 0; j < NN; ++j) {
            float e = expf(s[tid * 50 + j] - m);
            s[tid * 50 + j] = e;
            sum += e;
        }
        float inv = 1.0f / sum;
        for (int j = 0; j < NN; ++j) s[tid * 50 + j] *= inv;
    }
    __syncthreads();
    for (int idx = tid; idx < NN * HD; idx += 256) {
        int i = idx >> 5, d = idx & 31;
        float acc = 0.f;
        #pragma unroll
        for (int j = 0; j < NN; ++j) acc += s[i * 50 + j] * v[j * HD + d];
        attn_out[((size_t)(win * NN + i)) * CC + h * HD + d] = f2bf(acc);
    }
}

// ============ K5: residual (x + window-reversed proj) + LN2 -> h2 ============
__global__ __launch_bounds__(256) void resid_ln2(
    const void* __restrict__ x, const ushort_t* __restrict__ proj_tmp,
    const void* __restrict__ g2, const void* __restrict__ b2,
    ushort_t* __restrict__ h2, const int* __restrict__ flag) {
    const int f32m = *flag;
    int tok = blockIdx.x * 4 + (threadIdx.x >> 6);
    int lane = threadIdx.x & 63;
    size_t m = (size_t)tok2win(tok) * CC + lane * 2;
    size_t sx = (size_t)tok * CC + lane * 2;
    float x0, x1;
    if (f32m) {
        float2 t2 = *(const float2*)((const float*)x + sx);
        x0 = t2.x; x1 = t2.y;
    } else {
        ushort2 t2 = *(const ushort2*)((const ushort_t*)x + sx);
        x0 = bf2f(t2.x); x1 = bf2f(t2.y);
    }
    ushort2 pv = *(const ushort2*)&proj_tmp[m];
    float v0 = x0 + bf2f(pv.x);
    float v1 = x1 + bf2f(pv.y);
    float s = v0 + v1, sq = v0 * v0 + v1 * v1;
    #pragma unroll
    for (int o = 32; o > 0; o >>= 1) {
        s += __shfl_xor(s, o, 64);
        sq += __shfl_xor(sq, o, 64);
    }
    float mean = s * (1.0f / 128.0f);
    float var = sq * (1.0f / 128.0f) - mean * mean;
    float rstd = rsqrtf(var + 1e-5f);
    int c = lane * 2;
    float y0 = (v0 - mean) * rstd * ldf(g2, c, f32m) + ldf(b2, c, f32m);
    float y1 = (v1 - mean) * rstd * ldf(g2, c + 1, f32m) + ldf(b2, c + 1, f32m);
    ushort2 st; st.x = f2bf(y0); st.y = f2bf(y1);
    *(ushort2*)&h2[sx] = st;
}

// ============ launch ============
extern "C" void kernel_launch(void* const* d_in, const int* in_sizes, int n_in,
                              void* d_out, int out_size, void* d_ws, size_t ws_size,
                              hipStream_t stream) {
    const void* x       = d_in[0];
    const void* norm1_g = d_in[1];
    const void* norm1_b = d_in[2];
    const void* qkv_w   = d_in[3];
    const void* qkv_b   = d_in[4];
    const void* rpb     = d_in[5];
    const void* proj_w  = d_in[6];
    const void* proj_b  = d_in[7];
    const void* norm2_g = d_in[8];
    const void* norm2_b = d_in[9];
    const void* fc1_w   = d_in[10];
    const void* fc1_b   = d_in[11];
    const void* fc2_w   = d_in[12];
    const void* fc2_b   = d_in[13];
    const int*  rel_idx = (const int*)d_in[14];

    char* ws = (char*)d_ws;
    const size_t szB = (size_t)NTOK * CC * 2;   // 25,690,112
    // pick smallest chunk factor that fits ws_size
    int f = 1;
    while (f < 16) {
        size_t szA = (size_t)NTOK * 1024 / f;
        if (256 + szA + 2 * szB <= ws_size) break;
        f *= 2;
    }
    const size_t szA = (size_t)NTOK * 1024 / f;
    int Mc = NTOK / f;            // rows per chunk (multiple of 64 and of 49*windows)
    int wc = NWIN / f;            // windows per chunk

    int*      flag = (int*)ws;
    ushort_t* Areg = (ushort_t*)(ws + 256);
    ushort_t* Breg = (ushort_t*)(ws + 256 + szA);
    ushort_t* Creg = (ushort_t*)(ws + 256 + szA + szB);

    sniff_kernel<<<dim3(1), dim3(256), 0, stream>>>((const ushort_t*)x, flag);
    ln1_shift_window<<<dim3(NTOK / 4), dim3(256), 0, stream>>>(x, norm1_g, norm1_b, Breg, flag);
    for (int c = 0; c < f; ++c) {
        const ushort_t* wb = Breg + (size_t)c * Mc * CC;
        gemm_bt<0, 0><<<dim3(Mc / 64, 6), dim3(256), 0, stream>>>(
            wb, qkv_w, qkv_b, nullptr, nullptr, Areg, 384, 128, flag, 0);
        attn_kernel<<<dim3(wc * NHEAD), dim3(256), 0, stream>>>(
            Areg, rpb, rel_idx, Breg + (size_t)c * Mc * CC, flag);
        gemm_bt<0, 0><<<dim3(Mc / 64, 2), dim3(256), 0, stream>>>(
            Breg + (size_t)c * Mc * CC, proj_w, proj_b, nullptr, nullptr,
            Creg + (size_t)c * Mc * CC, 128, 128, flag, 0);
    }
    resid_ln2<<<dim3(NTOK / 4), dim3(256), 0, stream>>>(x, Creg, norm2_g, norm2_b, Breg, flag);
    for (int c = 0; c < f; ++c) {
        gemm_bt<1, 0><<<dim3(Mc / 64, 8), dim3(256), 0, stream>>>(
            Breg + (size_t)c * Mc * CC, fc1_w, fc1_b, nullptr, nullptr,
            Areg, 512, 128, flag, 0);
        gemm_bt<0, 1><<<dim3(Mc / 64, 2), dim3(256), 0, stream>>>(
            Areg, fc2_w, fc2_b, x, Creg, d_out, 128, 512, flag, c * Mc);
    }
}

// Round 3
// 534.088 us; speedup vs baseline: 1.2973x; 1.2973x over previous
//
#include <hip/hip_runtime.h>

typedef unsigned short ushort_t;
typedef unsigned int uint_t;

typedef __bf16 bf16x8 __attribute__((ext_vector_type(8)));
typedef float f32x4 __attribute__((ext_vector_type(4)));

static __device__ __forceinline__ float bf2f(ushort_t h) {
    return __uint_as_float(((uint_t)h) << 16);
}
static __device__ __forceinline__ ushort_t f2bf(float f) {
    uint_t u = __float_as_uint(f);
    u = u + 0x7FFFu + ((u >> 16) & 1u);   // round-to-nearest-even
    return (ushort_t)(u >> 16);
}
static __device__ __forceinline__ float ldf(const void* p, size_t i, int f32m) {
    return f32m ? ((const float*)p)[i] : bf2f(((const ushort_t*)p)[i]);
}

// ---------------- constants ----------------
#define BB 32
#define HH 56
#define WW_ 56
#define CC 128
#define NHEAD 4
#define WS 7
#define SS 3
#define LL (HH * WW_)           // 3136
#define NTOK (BB * LL)          // 100352
#define NWIN (BB * 64)          // 2048
#define NN 49
#define HD 32

static __device__ __forceinline__ int tok2win(int t) {
    int bb = t / LL;
    int rem = t - bb * LL;
    int hh = rem / WW_;
    int ww = rem - hh * WW_;
    int ip = hh - SS; if (ip < 0) ip += HH;
    int jp = ww - SS; if (jp < 0) jp += WW_;
    int wi = ip / WS, ti = ip - wi * WS;
    int wj = jp / WS, tj = jp - wj * WS;
    return ((bb << 6) + (wi << 3) + wj) * NN + ti * WS + tj;
}

// ============ K0: dtype sniffer (unchanged, worked in r2) ============
__global__ __launch_bounds__(256) void sniff_kernel(const ushort_t* __restrict__ x,
                                                    int* __restrict__ flag) {
    __shared__ int cnt, zcnt;
    if (threadIdx.x == 0) { cnt = 0; zcnt = 0; }
    __syncthreads();
    int c = 0, z = 0;
    for (int i = 0; i < 16; ++i) {
        ushort_t h = x[(threadIdx.x * 16 + i) * 2];
        int e = (h >> 7) & 0xFF;
        if (e >= 0xC0 || (e < 0x40 && (h & 0x7FFFu) != 0)) c++;
        if ((h & 0x7FFFu) == 0) z++;
    }
    atomicAdd(&cnt, c);
    atomicAdd(&zcnt, z);
    __syncthreads();
    if (threadIdx.x == 0) *flag = (cnt > 64 || zcnt > 2048) ? 1 : 0;
}

// ============ bias table: bias[h][i][j] (64x64 padded, fp32) ============
__global__ __launch_bounds__(256) void build_bias(
    const void* __restrict__ rpb, const int* __restrict__ rel_idx,
    float* __restrict__ bias, const int* __restrict__ flag) {
    const int f32m = *flag;
    int h = blockIdx.x;
    for (int idx = threadIdx.x; idx < 4096; idx += 256) {
        int i = idx >> 6, j = idx & 63;
        float v = 0.f;
        if (i < NN && j < NN)
            v = ldf(rpb, (size_t)rel_idx[i * NN + j] * NHEAD + h, f32m);
        bias[h * 4096 + idx] = v;
    }
}

// ============ K1: LN1 + cyclic shift + window partition ============
__global__ __launch_bounds__(256) void ln1_shift_window(
    const void* __restrict__ x, const void* __restrict__ g,
    const void* __restrict__ b, ushort_t* __restrict__ wbuf,
    const int* __restrict__ flag) {
    const int f32m = *flag;
    int wid = blockIdx.x * 4 + (threadIdx.x >> 6);
    int lane = threadIdx.x & 63;
    int win = wid / NN, t = wid - win * NN;
    int bb = win >> 6, wrem = win & 63;
    int wi = wrem >> 3, wj = wrem & 7;
    int ti = t / WS, tj = t - ti * WS;
    int hh = wi * WS + ti + SS; if (hh >= HH) hh -= HH;
    int ww = wj * WS + tj + SS; if (ww >= WW_) ww -= WW_;
    size_t src = ((size_t)bb * LL + hh * WW_ + ww) * CC + lane * 2;
    float v0, v1;
    if (f32m) {
        float2 t2 = *(const float2*)((const float*)x + src);
        v0 = t2.x; v1 = t2.y;
    } else {
        ushort2 t2 = *(const ushort2*)((const ushort_t*)x + src);
        v0 = bf2f(t2.x); v1 = bf2f(t2.y);
    }
    float s = v0 + v1, sq = v0 * v0 + v1 * v1;
    #pragma unroll
    for (int o = 32; o > 0; o >>= 1) {
        s += __shfl_xor(s, o, 64);
        sq += __shfl_xor(sq, o, 64);
    }
    float mean = s * (1.0f / 128.0f);
    float var = sq * (1.0f / 128.0f) - mean * mean;
    float rstd = rsqrtf(var + 1e-5f);
    int c = lane * 2;
    float y0 = (v0 - mean) * rstd * ldf(g, c, f32m) + ldf(b, c, f32m);
    float y1 = (v1 - mean) * rstd * ldf(g, c + 1, f32m) + ldf(b, c + 1, f32m);
    ushort2 st; st.x = f2bf(y0); st.y = f2bf(y1);
    *(ushort2*)&wbuf[(size_t)wid * CC + c] = st;
}

// ============ K2: 128x128-tile GEMM  out[m][n] = A[m][:]·W[n][:] + bias[n] ============
template <int ACT, int RESID>
__global__ __launch_bounds__(256) void gemm128(
    const ushort_t* __restrict__ A, const void* __restrict__ W,
    const void* __restrict__ bias, const void* __restrict__ xin,
    const ushort_t* __restrict__ proj, void* __restrict__ out,
    int N, int K, const int* __restrict__ flag, int grow0) {
    __shared__ __align__(16) ushort_t As[128 * 72];   // stride 72: 2-way banks (free)
    __shared__ __align__(16) ushort_t Ws[128 * 72];
    const int f32m = *flag;
    const int tid = threadIdx.x;
    const int m0 = blockIdx.x * 128;
    const int n0 = blockIdx.y * 128;
    const int wave = tid >> 6;
    const int lane = tid & 63;
    const int l16 = lane & 15;
    const int quad = lane >> 4;
    const int wm = (wave & 1) * 64;
    const int wn = (wave >> 1) * 64;

    f32x4 acc[4][4];
    #pragma unroll
    for (int i = 0; i < 4; ++i)
        #pragma unroll
        for (int j = 0; j < 4; ++j)
            acc[i][j] = (f32x4){0.f, 0.f, 0.f, 0.f};

    for (int kc = 0; kc < K; kc += 64) {
        #pragma unroll
        for (int u = tid; u < 1024; u += 256) {
            int row = u >> 3, ch = (u & 7) * 8;
            *(uint4*)&As[row * 72 + ch] =
                *(const uint4*)&A[(size_t)(m0 + row) * K + kc + ch];
        }
        if (f32m) {
            const float* Wf = (const float*)W;
            #pragma unroll
            for (int u = tid; u < 1024; u += 256) {
                int row = u >> 3, ch = (u & 7) * 8;
                const float* sp = &Wf[(size_t)(n0 + row) * K + kc + ch];
                float4 a0 = *(const float4*)sp;
                float4 a1 = *(const float4*)(sp + 4);
                ushort_t tmp[8] = {f2bf(a0.x), f2bf(a0.y), f2bf(a0.z), f2bf(a0.w),
                                   f2bf(a1.x), f2bf(a1.y), f2bf(a1.z), f2bf(a1.w)};
                *(uint4*)&Ws[row * 72 + ch] = *(const uint4*)tmp;
            }
        } else {
            const ushort_t* Wh = (const ushort_t*)W;
            #pragma unroll
            for (int u = tid; u < 1024; u += 256) {
                int row = u >> 3, ch = (u & 7) * 8;
                *(uint4*)&Ws[row * 72 + ch] =
                    *(const uint4*)&Wh[(size_t)(n0 + row) * K + kc + ch];
            }
        }
        __syncthreads();
        #pragma unroll
        for (int kk = 0; kk < 64; kk += 32) {
            bf16x8 af[4], bfr[4];
            #pragma unroll
            for (int i = 0; i < 4; ++i)
                af[i] = *(const bf16x8*)&As[(wm + 16 * i + l16) * 72 + kk + quad * 8];
            #pragma unroll
            for (int j = 0; j < 4; ++j)
                bfr[j] = *(const bf16x8*)&Ws[(wn + 16 * j + l16) * 72 + kk + quad * 8];
            #pragma unroll
            for (int i = 0; i < 4; ++i)
                #pragma unroll
                for (int j = 0; j < 4; ++j)
                    acc[i][j] = __builtin_amdgcn_mfma_f32_16x16x32_bf16(af[i], bfr[j], acc[i][j], 0, 0, 0);
        }
        __syncthreads();
    }
    #pragma unroll
    for (int j = 0; j < 4; ++j) {
        int col = n0 + wn + 16 * j + l16;
        float bv = ldf(bias, col, f32m);
        #pragma unroll
        for (int i = 0; i < 4; ++i) {
            #pragma unroll
            for (int r = 0; r < 4; ++r) {
                int row = m0 + wm + 16 * i + quad * 4 + r;
                float val = acc[i][j][r] + bv;
                if (ACT == 1) val = 0.5f * val * (1.0f + erff(val * 0.70710678118654752f));
                if (RESID == 1) {
                    int grow = grow0 + row;
                    int mwin = tok2win(grow);
                    val += ldf(xin, (size_t)grow * CC + col, f32m)
                         + bf2f(proj[(size_t)mwin * CC + col]);
                    size_t oi = (size_t)grow * CC + col;
                    if (f32m) ((float*)out)[oi] = val;
                    else      ((ushort_t*)out)[oi] = f2bf(val);
                } else {
                    ((ushort_t*)out)[(size_t)row * N + col] = f2bf(val);
                }
            }
        }
    }
}

// ============ K3: MFMA windowed attention — 1 block/window, 1 wave/head ============
// S = QK^T via 16 mfma (K=32 = head dim); softmax in registers (C/D layout);
// P -> LDS bf16; O^T = Vt·P^T (both frags contiguous); store O.
__global__ __launch_bounds__(256) void attn_mfma(
    const ushort_t* __restrict__ qkv, const float* __restrict__ bias,
    ushort_t* __restrict__ attn_out) {
    __shared__ __align__(16) ushort_t Vt[NHEAD][32 * 72];
    __shared__ __align__(16) ushort_t Ps[NHEAD][64 * 72];
    const int tid = threadIdx.x;
    const int wave = tid >> 6;          // head
    const int lane = tid & 63;
    const int l16 = lane & 15;
    const int quad = lane >> 4;
    const int win = blockIdx.x;
    const int h = wave;
    const float scale = 0.17677669529663687f;   // 32^-0.5

    ushort_t* vt = Vt[wave];
    ushort_t* ps = Ps[wave];

    // ---- stage V transposed: Vt[d][n] (n=0..48 from global, 49..63 zeroed)
    {
        int r0 = lane >> 2;
        int dc = (lane & 3) * 8;
        #pragma unroll
        for (int pass = 0; pass < 4; ++pass) {
            int i = pass * 16 + r0;
            if (i < NN) {
                const ushort_t* src = &qkv[((size_t)(win * NN + i)) * 384 + 256 + h * HD + dc];
                ushort4 a = *(const ushort4*)src;
                ushort4 b = *(const ushort4*)(src + 4);
                vt[(dc + 0) * 72 + i] = a.x; vt[(dc + 1) * 72 + i] = a.y;
                vt[(dc + 2) * 72 + i] = a.z; vt[(dc + 3) * 72 + i] = a.w;
                vt[(dc + 4) * 72 + i] = b.x; vt[(dc + 5) * 72 + i] = b.y;
                vt[(dc + 6) * 72 + i] = b.z; vt[(dc + 7) * 72 + i] = b.w;
            }
        }
        #pragma unroll
        for (int j = 0; j < 8; ++j) {
            int idx = lane * 8 + j;            // 0..511, need 480
            if (idx < 32 * 15) {
                int d = idx / 15, n = NN + idx - d * 15;
                vt[d * 72 + n] = 0;
            }
        }
    }

    // ---- S = QK^T  (frags straight from global; rows >=49 read next window: junk, discarded)
    f32x4 s[4][4];
    {
        bf16x8 qa[4], kb[4];
        #pragma unroll
        for (int t = 0; t < 4; ++t) {
            size_t rb = ((size_t)(win * NN + 16 * t + l16)) * 384 + h * HD + quad * 8;
            qa[t] = *(const bf16x8*)&qkv[rb];
            kb[t] = *(const bf16x8*)&qkv[rb + 128];
        }
        #pragma unroll
        for (int mi = 0; mi < 4; ++mi)
            #pragma unroll
            for (int ni = 0; ni < 4; ++ni) {
                f32x4 z = {0.f, 0.f, 0.f, 0.f};
                s[mi][ni] = __builtin_amdgcn_mfma_f32_16x16x32_bf16(qa[mi], kb[ni], z, 0, 0, 0);
            }
    }

    // ---- scale + bias (precomputed fp32 table, C/D addressing)
    const float* bh = bias + h * 4096;
    #pragma unroll
    for (int mi = 0; mi < 4; ++mi)
        #pragma unroll
        for (int ni = 0; ni < 4; ++ni)
            #pragma unroll
            for (int r = 0; r < 4; ++r)
                s[mi][ni][r] = s[mi][ni][r] * scale +
                               bh[(16 * mi + quad * 4 + r) * 64 + 16 * ni + l16];

    // ---- softmax over columns (ni regs x l16 lanes); col 48+l16 valid only for l16==0
    #pragma unroll
    for (int mi = 0; mi < 4; ++mi)
        #pragma unroll
        for (int r = 0; r < 4; ++r) {
            float m01 = fmaxf(s[mi][0][r], s[mi][1][r]);
            float m2 = s[mi][2][r];
            float m3 = (l16 == 0) ? s[mi][3][r] : -3.0e38f;
            float mx = fmaxf(fmaxf(m01, m2), m3);
            mx = fmaxf(mx, __shfl_xor(mx, 1));
            mx = fmaxf(mx, __shfl_xor(mx, 2));
            mx = fmaxf(mx, __shfl_xor(mx, 4));
            mx = fmaxf(mx, __shfl_xor(mx, 8));
            float e0 = expf(s[mi][0][r] - mx);
            float e1 = expf(s[mi][1][r] - mx);
            float e2 = expf(s[mi][2][r] - mx);
            float e3 = (l16 == 0) ? expf(s[mi][3][r] - mx) : 0.f;
            float sum = (e0 + e1) + (e2 + e3);
            sum += __shfl_xor(sum, 1);
            sum += __shfl_xor(sum, 2);
            sum += __shfl_xor(sum, 4);
            sum += __shfl_xor(sum, 8);
            float inv = 1.0f / sum;
            s[mi][0][r] = e0 * inv;
            s[mi][1][r] = e1 * inv;
            s[mi][2][r] = e2 * inv;
            s[mi][3][r] = e3 * inv;
        }

    // ---- P -> LDS (row-major [m][n], stride 72)
    #pragma unroll
    for (int mi = 0; mi < 4; ++mi)
        #pragma unroll
        for (int ni = 0; ni < 4; ++ni)
            #pragma unroll
            for (int r = 0; r < 4; ++r)
                ps[(16 * mi + quad * 4 + r) * 72 + 16 * ni + l16] = f2bf(s[mi][ni][r]);

    // ---- O^T = Vt · P^T : A-frag rows = d (Vt row-major), B-frag rows = m (P row-major)
    f32x4 o[2][4];
    #pragma unroll
    for (int it = 0; it < 2; ++it)
        #pragma unroll
        for (int jt = 0; jt < 4; ++jt)
            o[it][jt] = (f32x4){0.f, 0.f, 0.f, 0.f};
    #pragma unroll
    for (int k0 = 0; k0 < 64; k0 += 32) {
        bf16x8 va[2], pb[4];
        #pragma unroll
        for (int it = 0; it < 2; ++it)
            va[it] = *(const bf16x8*)&vt[(16 * it + l16) * 72 + k0 + quad * 8];
        #pragma unroll
        for (int jt = 0; jt < 4; ++jt)
            pb[jt] = *(const bf16x8*)&ps[(16 * jt + l16) * 72 + k0 + quad * 8];
        #pragma unroll
        for (int it = 0; it < 2; ++it)
            #pragma unroll
            for (int jt = 0; jt < 4; ++jt)
                o[it][jt] = __builtin_amdgcn_mfma_f32_16x16x32_bf16(va[it], pb[jt], o[it][jt], 0, 0, 0);
    }

    // ---- store: C/D of O^T: token m = 16*jt + l16, d = 16*it + quad*4 + r (4 contiguous)
    #pragma unroll
    for (int jt = 0; jt < 4; ++jt) {
        int m = 16 * jt + l16;
        if (m < NN) {
            #pragma unroll
            for (int it = 0; it < 2; ++it) {
                ushort4 st;
                st.x = f2bf(o[it][jt][0]);
                st.y = f2bf(o[it][jt][1]);
                st.z = f2bf(o[it][jt][2]);
                st.w = f2bf(o[it][jt][3]);
                *(ushort4*)&attn_out[((size_t)(win * NN + m)) * CC + h * HD + 16 * it + quad * 4] = st;
            }
        }
    }
}

// ============ K5: residual (x + window-reversed proj) + LN2 -> h2 ============
__global__ __launch_bounds__(256) void resid_ln2(
    const void* __restrict__ x, const ushort_t* __restrict__ proj_tmp,
    const void* __restrict__ g2, const void* __restrict__ b2,
    ushort_t* __restrict__ h2, const int* __restrict__ flag) {
    const int f32m = *flag;
    int tok = blockIdx.x * 4 + (threadIdx.x >> 6);
    int lane = threadIdx.x & 63;
    size_t m = (size_t)tok2win(tok) * CC + lane * 2;
    size_t sx = (size_t)tok * CC + lane * 2;
    float x0, x1;
    if (f32m) {
        float2 t2 = *(const float2*)((const float*)x + sx);
        x0 = t2.x; x1 = t2.y;
    } else {
        ushort2 t2 = *(const ushort2*)((const ushort_t*)x + sx);
        x0 = bf2f(t2.x); x1 = bf2f(t2.y);
    }
    ushort2 pv = *(const ushort2*)&proj_tmp[m];
    float v0 = x0 + bf2f(pv.x);
    float v1 = x1 + bf2f(pv.y);
    float s = v0 + v1, sq = v0 * v0 + v1 * v1;
    #pragma unroll
    for (int o = 32; o > 0; o >>= 1) {
        s += __shfl_xor(s, o, 64);
        sq += __shfl_xor(sq, o, 64);
    }
    float mean = s * (1.0f / 128.0f);
    float var = sq * (1.0f / 128.0f) - mean * mean;
    float rstd = rsqrtf(var + 1e-5f);
    int c = lane * 2;
    float y0 = (v0 - mean) * rstd * ldf(g2, c, f32m) + ldf(b2, c, f32m);
    float y1 = (v1 - mean) * rstd * ldf(g2, c + 1, f32m) + ldf(b2, c + 1, f32m);
    ushort2 st; st.x = f2bf(y0); st.y = f2bf(y1);
    *(ushort2*)&h2[sx] = st;
}

// ============ launch ============
extern "C" void kernel_launch(void* const* d_in, const int* in_sizes, int n_in,
                              void* d_out, int out_size, void* d_ws, size_t ws_size,
                              hipStream_t stream) {
    const void* x       = d_in[0];
    const void* norm1_g = d_in[1];
    const void* norm1_b = d_in[2];
    const void* qkv_w   = d_in[3];
    const void* qkv_b   = d_in[4];
    const void* rpb     = d_in[5];
    const void* proj_w  = d_in[6];
    const void* proj_b  = d_in[7];
    const void* norm2_g = d_in[8];
    const void* norm2_b = d_in[9];
    const void* fc1_w   = d_in[10];
    const void* fc1_b   = d_in[11];
    const void* fc2_w   = d_in[12];
    const void* fc2_b   = d_in[13];
    const int*  rel_idx = (const int*)d_in[14];

    char* ws = (char*)d_ws;
    const size_t szB = (size_t)NTOK * CC * 2;       // 25,690,112
    const size_t base = 4096 + 65536;               // flag + bias table
    int f = 1;
    while (f < 16) {
        size_t szA = (size_t)NTOK * 1024 / f;
        if (base + szA + 2 * szB <= ws_size) break;
        f *= 2;
    }
    const size_t szA = (size_t)NTOK * 1024 / f;
    int Mc = NTOK / f;                              // multiple of 128 for all f in {1..16}
    int wc = NWIN / f;

    int*      flag  = (int*)ws;
    float*    biasT = (float*)(ws + 4096);
    ushort_t* Areg  = (ushort_t*)(ws + base);
    ushort_t* Breg  = (ushort_t*)(ws + base + szA);
    ushort_t* Creg  = (ushort_t*)(ws + base + szA + szB);

    sniff_kernel<<<dim3(1), dim3(256), 0, stream>>>((const ushort_t*)x, flag);
    build_bias<<<dim3(NHEAD), dim3(256), 0, stream>>>(rpb, rel_idx, biasT, flag);
    ln1_shift_window<<<dim3(NTOK / 4), dim3(256), 0, stream>>>(x, norm1_g, norm1_b, Breg, flag);
    for (int c = 0; c < f; ++c) {
        ushort_t* wb = Breg + (size_t)c * Mc * CC;
        gemm128<0, 0><<<dim3(Mc / 128, 3), dim3(256), 0, stream>>>(
            wb, qkv_w, qkv_b, nullptr, nullptr, Areg, 384, 128, flag, 0);
        attn_mfma<<<dim3(wc), dim3(256), 0, stream>>>(Areg, biasT, wb);
        gemm128<0, 0><<<dim3(Mc / 128, 1), dim3(256), 0, stream>>>(
            wb, proj_w, proj_b, nullptr, nullptr,
            Creg + (size_t)c * Mc * CC, 128, 128, flag, 0);
    }
    resid_ln2<<<dim3(NTOK / 4), dim3(256), 0, stream>>>(x, Creg, norm2_g, norm2_b, Breg, flag);
    for (int c = 0; c < f; ++c) {
        gemm128<1, 0><<<dim3(Mc / 128, 4), dim3(256), 0, stream>>>(
            Breg + (size_t)c * Mc * CC, fc1_w, fc1_b, nullptr, nullptr,
            Areg, 512, 128, flag, 0);
        gemm128<0, 1><<<dim3(Mc / 128, 1), dim3(256), 0, stream>>>(
            Areg, fc2_w, fc2_b, x, Creg, d_out, 128, 512, flag, c * Mc);
    }
}

// Round 4
// 430.284 us; speedup vs baseline: 1.6102x; 1.2412x over previous
//
#include <hip/hip_runtime.h>

typedef unsigned short ushort_t;
typedef unsigned int uint_t;

typedef __bf16 bf16x8 __attribute__((ext_vector_type(8)));
typedef float f32x4 __attribute__((ext_vector_type(4)));

static __device__ __forceinline__ float bf2f(ushort_t h) {
    return __uint_as_float(((uint_t)h) << 16);
}
static __device__ __forceinline__ ushort_t f2bf(float f) {
    uint_t u = __float_as_uint(f);
    u = u + 0x7FFFu + ((u >> 16) & 1u);   // round-to-nearest-even
    return (ushort_t)(u >> 16);
}

// ---------------- constants ----------------
#define BB 32
#define HH 56
#define WW_ 56
#define CC 128
#define NHEAD 4
#define WS 7
#define SS 3
#define LL (HH * WW_)           // 3136
#define NTOK (BB * LL)          // 100352
#define NWIN (BB * 64)          // 2048
#define NN 49
#define HD 32

static __device__ __forceinline__ int tok2win(int t) {
    int bb = t / LL;
    int rem = t - bb * LL;
    int hh = rem / WW_;
    int ww = rem - hh * WW_;
    int ip = hh - SS; if (ip < 0) ip += HH;
    int jp = ww - SS; if (jp < 0) jp += WW_;
    int wi = ip / WS, ti = ip - wi * WS;
    int wj = jp / WS, tj = jp - wj * WS;
    return ((bb << 6) + (wi << 3) + wj) * NN + ti * WS + tj;
}

// ============ weight pre-convert: fp32 -> bf16 (once per call, 0.8 MB read) ============
// layout: [qkv_w 49152][proj_w 16384][fc1_w 65536][fc2_w 65536]
__global__ __launch_bounds__(256) void prep_weights(
    const float* __restrict__ qkv_w, const float* __restrict__ proj_w,
    const float* __restrict__ fc1_w, const float* __restrict__ fc2_w,
    ushort_t* __restrict__ dst) {
    int i = blockIdx.x * 256 + threadIdx.x;   // 0 .. 196607
    const float* src;
    int off;
    if (i < 49152)        { src = qkv_w;  off = i; }
    else if (i < 65536)   { src = proj_w; off = i - 49152; }
    else if (i < 131072)  { src = fc1_w;  off = i - 65536; }
    else                  { src = fc2_w;  off = i - 131072; }
    dst[i] = f2bf(src[off]);
}

// ============ bias table: bias[h][i][j] (64x64 padded, fp32) ============
__global__ __launch_bounds__(256) void build_bias(
    const float* __restrict__ rpb, const int* __restrict__ rel_idx,
    float* __restrict__ bias) {
    int h = blockIdx.x;
    for (int idx = threadIdx.x; idx < 4096; idx += 256) {
        int i = idx >> 6, j = idx & 63;
        float v = 0.f;
        if (i < NN && j < NN)
            v = rpb[(size_t)rel_idx[i * NN + j] * NHEAD + h];
        bias[h * 4096 + idx] = v;
    }
}

// ============ K1: LN1 + cyclic shift + window partition (fp32 in, bf16 out) ============
__global__ __launch_bounds__(256) void ln1_shift_window(
    const float* __restrict__ x, const float* __restrict__ g,
    const float* __restrict__ b, ushort_t* __restrict__ wbuf) {
    int wid = blockIdx.x * 4 + (threadIdx.x >> 6);
    int lane = threadIdx.x & 63;
    int win = wid / NN, t = wid - win * NN;
    int bb = win >> 6, wrem = win & 63;
    int wi = wrem >> 3, wj = wrem & 7;
    int ti = t / WS, tj = t - ti * WS;
    int hh = wi * WS + ti + SS; if (hh >= HH) hh -= HH;
    int ww = wj * WS + tj + SS; if (ww >= WW_) ww -= WW_;
    size_t src = ((size_t)bb * LL + hh * WW_ + ww) * CC + lane * 2;
    float2 t2 = *(const float2*)(x + src);
    float v0 = t2.x, v1 = t2.y;
    float s = v0 + v1, sq = v0 * v0 + v1 * v1;
    #pragma unroll
    for (int o = 32; o > 0; o >>= 1) {
        s += __shfl_xor(s, o, 64);
        sq += __shfl_xor(sq, o, 64);
    }
    float mean = s * (1.0f / 128.0f);
    float var = sq * (1.0f / 128.0f) - mean * mean;
    float rstd = rsqrtf(var + 1e-5f);
    int c = lane * 2;
    float y0 = (v0 - mean) * rstd * g[c] + b[c];
    float y1 = (v1 - mean) * rstd * g[c + 1] + b[c + 1];
    ushort2 st; st.x = f2bf(y0); st.y = f2bf(y1);
    *(ushort2*)&wbuf[(size_t)wid * CC + c] = st;
}

// ============ K2: 128x128-tile GEMM (A bf16, W bf16 preconverted, bias fp32) ============
__global__ __launch_bounds__(256) void gemm128(
    const ushort_t* __restrict__ A, const ushort_t* __restrict__ W,
    const float* __restrict__ bias, ushort_t* __restrict__ out,
    int N, int K) {
    __shared__ __align__(16) ushort_t As[128 * 72];
    __shared__ __align__(16) ushort_t Ws[128 * 72];
    const int tid = threadIdx.x;
    const int m0 = blockIdx.x * 128;
    const int n0 = blockIdx.y * 128;
    const int wave = tid >> 6;
    const int lane = tid & 63;
    const int l16 = lane & 15;
    const int quad = lane >> 4;
    const int wm = (wave & 1) * 64;
    const int wn = (wave >> 1) * 64;

    f32x4 acc[4][4];
    #pragma unroll
    for (int i = 0; i < 4; ++i)
        #pragma unroll
        for (int j = 0; j < 4; ++j)
            acc[i][j] = (f32x4){0.f, 0.f, 0.f, 0.f};

    for (int kc = 0; kc < K; kc += 64) {
        #pragma unroll
        for (int u = tid; u < 1024; u += 256) {
            int row = u >> 3, ch = (u & 7) * 8;
            *(uint4*)&As[row * 72 + ch] =
                *(const uint4*)&A[(size_t)(m0 + row) * K + kc + ch];
            *(uint4*)&Ws[row * 72 + ch] =
                *(const uint4*)&W[(size_t)(n0 + row) * K + kc + ch];
        }
        __syncthreads();
        #pragma unroll
        for (int kk = 0; kk < 64; kk += 32) {
            bf16x8 af[4], bfr[4];
            #pragma unroll
            for (int i = 0; i < 4; ++i)
                af[i] = *(const bf16x8*)&As[(wm + 16 * i + l16) * 72 + kk + quad * 8];
            #pragma unroll
            for (int j = 0; j < 4; ++j)
                bfr[j] = *(const bf16x8*)&Ws[(wn + 16 * j + l16) * 72 + kk + quad * 8];
            #pragma unroll
            for (int i = 0; i < 4; ++i)
                #pragma unroll
                for (int j = 0; j < 4; ++j)
                    acc[i][j] = __builtin_amdgcn_mfma_f32_16x16x32_bf16(af[i], bfr[j], acc[i][j], 0, 0, 0);
        }
        __syncthreads();
    }
    #pragma unroll
    for (int j = 0; j < 4; ++j) {
        int col = n0 + wn + 16 * j + l16;
        float bv = bias[col];
        #pragma unroll
        for (int i = 0; i < 4; ++i)
            #pragma unroll
            for (int r = 0; r < 4; ++r) {
                int row = m0 + wm + 16 * i + quad * 4 + r;
                out[(size_t)row * N + col] = f2bf(acc[i][j][r] + bv);
            }
    }
}

// ============ K3: MFMA windowed attention (unchanged from r3, verified) ============
__global__ __launch_bounds__(256) void attn_mfma(
    const ushort_t* __restrict__ qkv, const float* __restrict__ bias,
    ushort_t* __restrict__ attn_out) {
    __shared__ __align__(16) ushort_t Vt[NHEAD][32 * 72];
    __shared__ __align__(16) ushort_t Ps[NHEAD][64 * 72];
    const int tid = threadIdx.x;
    const int wave = tid >> 6;
    const int lane = tid & 63;
    const int l16 = lane & 15;
    const int quad = lane >> 4;
    const int win = blockIdx.x;
    const int h = wave;
    const float scale = 0.17677669529663687f;

    ushort_t* vt = Vt[wave];
    ushort_t* ps = Ps[wave];

    {
        int r0 = lane >> 2;
        int dc = (lane & 3) * 8;
        #pragma unroll
        for (int pass = 0; pass < 4; ++pass) {
            int i = pass * 16 + r0;
            if (i < NN) {
                const ushort_t* src = &qkv[((size_t)(win * NN + i)) * 384 + 256 + h * HD + dc];
                ushort4 a = *(const ushort4*)src;
                ushort4 b = *(const ushort4*)(src + 4);
                vt[(dc + 0) * 72 + i] = a.x; vt[(dc + 1) * 72 + i] = a.y;
                vt[(dc + 2) * 72 + i] = a.z; vt[(dc + 3) * 72 + i] = a.w;
                vt[(dc + 4) * 72 + i] = b.x; vt[(dc + 5) * 72 + i] = b.y;
                vt[(dc + 6) * 72 + i] = b.z; vt[(dc + 7) * 72 + i] = b.w;
            }
        }
        #pragma unroll
        for (int j = 0; j < 8; ++j) {
            int idx = lane * 8 + j;
            if (idx < 32 * 15) {
                int d = idx / 15, n = NN + idx - d * 15;
                vt[d * 72 + n] = 0;
            }
        }
    }

    f32x4 s[4][4];
    {
        bf16x8 qa[4], kb[4];
        #pragma unroll
        for (int t = 0; t < 4; ++t) {
            size_t rb = ((size_t)(win * NN + 16 * t + l16)) * 384 + h * HD + quad * 8;
            qa[t] = *(const bf16x8*)&qkv[rb];
            kb[t] = *(const bf16x8*)&qkv[rb + 128];
        }
        #pragma unroll
        for (int mi = 0; mi < 4; ++mi)
            #pragma unroll
            for (int ni = 0; ni < 4; ++ni) {
                f32x4 z = {0.f, 0.f, 0.f, 0.f};
                s[mi][ni] = __builtin_amdgcn_mfma_f32_16x16x32_bf16(qa[mi], kb[ni], z, 0, 0, 0);
            }
    }

    const float* bh = bias + h * 4096;
    #pragma unroll
    for (int mi = 0; mi < 4; ++mi)
        #pragma unroll
        for (int ni = 0; ni < 4; ++ni)
            #pragma unroll
            for (int r = 0; r < 4; ++r)
                s[mi][ni][r] = s[mi][ni][r] * scale +
                               bh[(16 * mi + quad * 4 + r) * 64 + 16 * ni + l16];

    #pragma unroll
    for (int mi = 0; mi < 4; ++mi)
        #pragma unroll
        for (int r = 0; r < 4; ++r) {
            float m01 = fmaxf(s[mi][0][r], s[mi][1][r]);
            float m2 = s[mi][2][r];
            float m3 = (l16 == 0) ? s[mi][3][r] : -3.0e38f;
            float mx = fmaxf(fmaxf(m01, m2), m3);
            mx = fmaxf(mx, __shfl_xor(mx, 1));
            mx = fmaxf(mx, __shfl_xor(mx, 2));
            mx = fmaxf(mx, __shfl_xor(mx, 4));
            mx = fmaxf(mx, __shfl_xor(mx, 8));
            float e0 = expf(s[mi][0][r] - mx);
            float e1 = expf(s[mi][1][r] - mx);
            float e2 = expf(s[mi][2][r] - mx);
            float e3 = (l16 == 0) ? expf(s[mi][3][r] - mx) : 0.f;
            float sum = (e0 + e1) + (e2 + e3);
            sum += __shfl_xor(sum, 1);
            sum += __shfl_xor(sum, 2);
            sum += __shfl_xor(sum, 4);
            sum += __shfl_xor(sum, 8);
            float inv = 1.0f / sum;
            s[mi][0][r] = e0 * inv;
            s[mi][1][r] = e1 * inv;
            s[mi][2][r] = e2 * inv;
            s[mi][3][r] = e3 * inv;
        }

    #pragma unroll
    for (int mi = 0; mi < 4; ++mi)
        #pragma unroll
        for (int ni = 0; ni < 4; ++ni)
            #pragma unroll
            for (int r = 0; r < 4; ++r)
                ps[(16 * mi + quad * 4 + r) * 72 + 16 * ni + l16] = f2bf(s[mi][ni][r]);

    f32x4 o[2][4];
    #pragma unroll
    for (int it = 0; it < 2; ++it)
        #pragma unroll
        for (int jt = 0; jt < 4; ++jt)
            o[it][jt] = (f32x4){0.f, 0.f, 0.f, 0.f};
    #pragma unroll
    for (int k0 = 0; k0 < 64; k0 += 32) {
        bf16x8 va[2], pb[4];
        #pragma unroll
        for (int it = 0; it < 2; ++it)
            va[it] = *(const bf16x8*)&vt[(16 * it + l16) * 72 + k0 + quad * 8];
        #pragma unroll
        for (int jt = 0; jt < 4; ++jt)
            pb[jt] = *(const bf16x8*)&ps[(16 * jt + l16) * 72 + k0 + quad * 8];
        #pragma unroll
        for (int it = 0; it < 2; ++it)
            #pragma unroll
            for (int jt = 0; jt < 4; ++jt)
                o[it][jt] = __builtin_amdgcn_mfma_f32_16x16x32_bf16(va[it], pb[jt], o[it][jt], 0, 0, 0);
    }

    #pragma unroll
    for (int jt = 0; jt < 4; ++jt) {
        int m = 16 * jt + l16;
        if (m < NN) {
            #pragma unroll
            for (int it = 0; it < 2; ++it) {
                ushort4 st;
                st.x = f2bf(o[it][jt][0]);
                st.y = f2bf(o[it][jt][1]);
                st.z = f2bf(o[it][jt][2]);
                st.w = f2bf(o[it][jt][3]);
                *(ushort4*)&attn_out[((size_t)(win * NN + m)) * CC + h * HD + 16 * it + quad * 4] = st;
            }
        }
    }
}

// ============ K4: fused resid + LN2 + fc1 + GELU + fc2 + resid ============
// Block = 128 token rows. Prologue: x2 = x + winrev(proj) -> d_out (fp32) and
// h2 = LN2(x2) -> LDS. Loop over 4 fc1-chunks: P = gelu(h2 @ W1c^T + b1c),
// out-acc += P @ W2c^T. W frags read directly from global bf16 (L2-resident).
// Epilogue: d_out += mlp (RMW, same-block rows, L2-hot).
__global__ __launch_bounds__(256) void mlp_fused(
    const float* __restrict__ x, const ushort_t* __restrict__ proj,
    const float* __restrict__ g2, const float* __restrict__ b2,
    const ushort_t* __restrict__ w1, const float* __restrict__ b1,
    const ushort_t* __restrict__ w2, const float* __restrict__ bias2,
    float* __restrict__ out) {
    __shared__ __align__(16) ushort_t H2[128 * 136];
    __shared__ __align__(16) ushort_t PS[128 * 136];
    const int tid = threadIdx.x;
    const int m0 = blockIdx.x * 128;
    const int wave = tid >> 6;
    const int lane = tid & 63;
    const int l16 = lane & 15;
    const int quad = lane >> 4;
    const int wm = (wave & 1) * 64;
    const int wn = (wave >> 1) * 64;

    // ---- prologue: residual + LN2 ----
    {
        int row = tid >> 1;
        int half = (tid & 1) * 64;
        int grow = m0 + row;
        int mwin = tok2win(grow);
        const float* xp = x + (size_t)grow * CC + half;
        const ushort_t* pp = proj + (size_t)mwin * CC + half;
        float v[64];
        float s = 0.f, sq = 0.f;
        #pragma unroll
        for (int i = 0; i < 8; ++i) {
            float4 a0 = *(const float4*)(xp + i * 8);
            float4 a1 = *(const float4*)(xp + i * 8 + 4);
            ushort4 p0 = *(const ushort4*)(pp + i * 8);
            ushort4 p1 = *(const ushort4*)(pp + i * 8 + 4);
            v[i * 8 + 0] = a0.x + bf2f(p0.x); v[i * 8 + 1] = a0.y + bf2f(p0.y);
            v[i * 8 + 2] = a0.z + bf2f(p0.z); v[i * 8 + 3] = a0.w + bf2f(p0.w);
            v[i * 8 + 4] = a1.x + bf2f(p1.x); v[i * 8 + 5] = a1.y + bf2f(p1.y);
            v[i * 8 + 6] = a1.z + bf2f(p1.z); v[i * 8 + 7] = a1.w + bf2f(p1.w);
            #pragma unroll
            for (int j = 0; j < 8; ++j) { s += v[i * 8 + j]; sq += v[i * 8 + j] * v[i * 8 + j]; }
        }
        // write x2 to out (fp32)
        float* op = out + (size_t)grow * CC + half;
        #pragma unroll
        for (int i = 0; i < 16; ++i)
            *(float4*)(op + i * 4) = *(const float4*)(v + i * 4);
        s += __shfl_xor(s, 1);
        sq += __shfl_xor(sq, 1);
        float mean = s * (1.0f / 128.0f);
        float var = sq * (1.0f / 128.0f) - mean * mean;
        float rstd = rsqrtf(var + 1e-5f);
        #pragma unroll
        for (int i = 0; i < 8; ++i) {
            ushort_t tmp[8];
            #pragma unroll
            for (int j = 0; j < 8; ++j) {
                int c = half + i * 8 + j;
                tmp[j] = f2bf((v[i * 8 + j] - mean) * rstd * g2[c] + b2[c]);
            }
            *(uint4*)&H2[row * 136 + half + i * 8] = *(const uint4*)tmp;
        }
    }
    __syncthreads();

    f32x4 acc[4][4];
    #pragma unroll
    for (int i = 0; i < 4; ++i)
        #pragma unroll
        for (int j = 0; j < 4; ++j)
            acc[i][j] = (f32x4){0.f, 0.f, 0.f, 0.f};

    for (int c = 0; c < 4; ++c) {
        // ---- MFMA1: P = h2 @ W1c^T ----
        f32x4 s1[4][4];
        #pragma unroll
        for (int i = 0; i < 4; ++i)
            #pragma unroll
            for (int j = 0; j < 4; ++j)
                s1[i][j] = (f32x4){0.f, 0.f, 0.f, 0.f};
        #pragma unroll
        for (int kc = 0; kc < 128; kc += 32) {
            bf16x8 af[4], bfr[4];
            #pragma unroll
            for (int i = 0; i < 4; ++i)
                af[i] = *(const bf16x8*)&H2[(wm + 16 * i + l16) * 136 + kc + quad * 8];
            #pragma unroll
            for (int j = 0; j < 4; ++j)
                bfr[j] = *(const bf16x8*)&w1[(size_t)(c * 128 + wn + 16 * j + l16) * 128 + kc + quad * 8];
            #pragma unroll
            for (int i = 0; i < 4; ++i)
                #pragma unroll
                for (int j = 0; j < 4; ++j)
                    s1[i][j] = __builtin_amdgcn_mfma_f32_16x16x32_bf16(af[i], bfr[j], s1[i][j], 0, 0, 0);
        }
        // ---- bias + GELU (sigma-form tanh approx) ----
        #pragma unroll
        for (int j = 0; j < 4; ++j) {
            float bv = b1[c * 128 + wn + 16 * j + l16];
            #pragma unroll
            for (int i = 0; i < 4; ++i)
                #pragma unroll
                for (int r = 0; r < 4; ++r) {
                    float u = s1[i][j][r] + bv;
                    float z = 1.5957691216f * u * (1.0f + 0.044715f * u * u);
                    s1[i][j][r] = u / (1.0f + __expf(-z));
                }
        }
        __syncthreads();   // previous chunk's MFMA2 done reading PS
        #pragma unroll
        for (int i = 0; i < 4; ++i)
            #pragma unroll
            for (int j = 0; j < 4; ++j)
                #pragma unroll
                for (int r = 0; r < 4; ++r)
                    PS[(wm + 16 * i + quad * 4 + r) * 136 + wn + 16 * j + l16] = f2bf(s1[i][j][r]);
        __syncthreads();
        // ---- MFMA2: out += P @ W2c^T ----
        #pragma unroll
        for (int kk = 0; kk < 128; kk += 32) {
            bf16x8 af[4], bfr[4];
            #pragma unroll
            for (int i = 0; i < 4; ++i)
                af[i] = *(const bf16x8*)&PS[(wm + 16 * i + l16) * 136 + kk + quad * 8];
            #pragma unroll
            for (int j = 0; j < 4; ++j)
                bfr[j] = *(const bf16x8*)&w2[(size_t)(wn + 16 * j + l16) * 512 + c * 128 + kk + quad * 8];
            #pragma unroll
            for (int i = 0; i < 4; ++i)
                #pragma unroll
                for (int j = 0; j < 4; ++j)
                    acc[i][j] = __builtin_amdgcn_mfma_f32_16x16x32_bf16(af[i], bfr[j], acc[i][j], 0, 0, 0);
        }
    }

    // ---- epilogue: RMW d_out (x2 written by this block in prologue) ----
    #pragma unroll
    for (int j = 0; j < 4; ++j) {
        int col = wn + 16 * j + l16;
        float bv = bias2[col];
        #pragma unroll
        for (int i = 0; i < 4; ++i)
            #pragma unroll
            for (int r = 0; r < 4; ++r) {
                int grow = m0 + wm + 16 * i + quad * 4 + r;
                size_t oi = (size_t)grow * CC + col;
                out[oi] += acc[i][j][r] + bv;
            }
    }
}

// ============ launch ============
extern "C" void kernel_launch(void* const* d_in, const int* in_sizes, int n_in,
                              void* d_out, int out_size, void* d_ws, size_t ws_size,
                              hipStream_t stream) {
    const float* x       = (const float*)d_in[0];
    const float* norm1_g = (const float*)d_in[1];
    const float* norm1_b = (const float*)d_in[2];
    const float* qkv_w   = (const float*)d_in[3];
    const float* qkv_b   = (const float*)d_in[4];
    const float* rpb     = (const float*)d_in[5];
    const float* proj_w  = (const float*)d_in[6];
    const float* proj_b  = (const float*)d_in[7];
    const float* norm2_g = (const float*)d_in[8];
    const float* norm2_b = (const float*)d_in[9];
    const float* fc1_w   = (const float*)d_in[10];
    const float* fc1_b   = (const float*)d_in[11];
    const float* fc2_w   = (const float*)d_in[12];
    const float* fc2_b   = (const float*)d_in[13];
    const int*   rel_idx = (const int*)d_in[14];

    char* ws = (char*)d_ws;
    // [biasT 64K][weights bf16 ~393K] -> base 512K
    float*    biasT = (float*)ws;
    ushort_t* wall  = (ushort_t*)(ws + 65536);
    ushort_t* wqkv  = wall;
    ushort_t* wproj = wall + 49152;
    ushort_t* wfc1  = wall + 65536;
    ushort_t* wfc2  = wall + 131072;
    const size_t base = 524288;
    const size_t szB = (size_t)NTOK * CC * 2;        // 25.7 MB
    int f = 1;
    while (f < 16) {
        size_t szA = (size_t)NTOK * 384 * 2 / f;
        if (base + szA + 2 * szB <= ws_size) break;
        f *= 2;
    }
    const size_t szA = (size_t)NTOK * 384 * 2 / f;
    int Mc = NTOK / f;
    int wc = NWIN / f;

    ushort_t* Areg = (ushort_t*)(ws + base);          // qkv bf16 (chunk)
    ushort_t* Breg = (ushort_t*)(ws + base + szA);    // wbuf / attn_out
    ushort_t* Creg = (ushort_t*)(ws + base + szA + szB); // proj out

    prep_weights<<<dim3(768), dim3(256), 0, stream>>>(qkv_w, proj_w, fc1_w, fc2_w, wall);
    build_bias<<<dim3(NHEAD), dim3(256), 0, stream>>>(rpb, rel_idx, biasT);
    ln1_shift_window<<<dim3(NTOK / 4), dim3(256), 0, stream>>>(x, norm1_g, norm1_b, Breg);
    for (int c = 0; c < f; ++c) {
        ushort_t* wb = Breg + (size_t)c * Mc * CC;
        gemm128<<<dim3(Mc / 128, 3), dim3(256), 0, stream>>>(wb, wqkv, qkv_b, Areg, 384, 128);
        attn_mfma<<<dim3(wc), dim3(256), 0, stream>>>(Areg, biasT, wb);
        gemm128<<<dim3(Mc / 128, 1), dim3(256), 0, stream>>>(
            wb, wproj, proj_b, Creg + (size_t)c * Mc * CC, 128, 128);
    }
    mlp_fused<<<dim3(NTOK / 128), dim3(256), 0, stream>>>(
        x, Creg, norm2_g, norm2_b, wfc1, fc1_b, wfc2, fc2_b, (float*)d_out);
}

// Round 5
// 362.161 us; speedup vs baseline: 1.9131x; 1.1881x over previous
//
#include <hip/hip_runtime.h>

typedef unsigned short ushort_t;
typedef unsigned int uint_t;

typedef __bf16 bf16x8 __attribute__((ext_vector_type(8)));
typedef float f32x4 __attribute__((ext_vector_type(4)));

static __device__ __forceinline__ float bf2f(ushort_t h) {
    return __uint_as_float(((uint_t)h) << 16);
}
static __device__ __forceinline__ ushort_t f2bf(float f) {
    uint_t u = __float_as_uint(f);
    u = u + 0x7FFFu + ((u >> 16) & 1u);
    return (ushort_t)(u >> 16);
}

// ---------------- constants ----------------
#define BB 32
#define HH 56
#define WW_ 56
#define CC 128
#define NHEAD 4
#define WS 7
#define SS 3
#define LL (HH * WW_)           // 3136
#define NTOK (BB * LL)          // 100352
#define NWIN (BB * 64)          // 2048
#define NN 49
#define HD 32

// windowed token -> global token (forward map, same as r2-r4 ln1 source map)
static __device__ __forceinline__ int win2tok(int wid) {
    int win = wid / NN, t = wid - win * NN;
    int bb = win >> 6, wrem = win & 63;
    int wi = wrem >> 3, wj = wrem & 7;
    int ti = t / WS, tj = t - ti * WS;
    int hh = wi * WS + ti + SS; if (hh >= HH) hh -= HH;
    int ww = wj * WS + tj + SS; if (ww >= WW_) ww -= WW_;
    return bb * LL + hh * WW_ + ww;
}

// ============ weight pre-convert fp32->bf16 ============
__global__ __launch_bounds__(256) void prep_weights(
    const float* __restrict__ qkv_w, const float* __restrict__ proj_w,
    const float* __restrict__ fc1_w, const float* __restrict__ fc2_w,
    ushort_t* __restrict__ dst) {
    int i = blockIdx.x * 256 + threadIdx.x;   // 0 .. 196607
    const float* src;
    int off;
    if (i < 49152)        { src = qkv_w;  off = i; }
    else if (i < 65536)   { src = proj_w; off = i - 49152; }
    else if (i < 131072)  { src = fc1_w;  off = i - 65536; }
    else                  { src = fc2_w;  off = i - 131072; }
    dst[i] = f2bf(src[off]);
}

// ============ bias table: bias[h][i][j] (64x64 padded, fp32) ============
__global__ __launch_bounds__(256) void build_bias(
    const float* __restrict__ rpb, const int* __restrict__ rel_idx,
    float* __restrict__ bias) {
    int h = blockIdx.x;
    for (int idx = threadIdx.x; idx < 4096; idx += 256) {
        int i = idx >> 6, j = idx & 63;
        float v = 0.f;
        if (i < NN && j < NN)
            v = rpb[(size_t)rel_idx[i * NN + j] * NHEAD + h];
        bias[h * 4096 + idx] = v;
    }
}

// ============ K1: fused LN1+shift+window + QKV GEMM ============
// Block = 128 windowed tokens. Prologue: load x rows (shift map), LN1 -> LDS bf16.
// Then 3 N-chunks of 128: B-frags straight from global bf16 weights (L2-hot).
__global__ __launch_bounds__(256) void qkv_fused(
    const float* __restrict__ x, const float* __restrict__ g1,
    const float* __restrict__ b1, const ushort_t* __restrict__ wq,
    const float* __restrict__ qkv_b, ushort_t* __restrict__ qkv,
    int wid0) {
    __shared__ __align__(16) ushort_t As[128 * 136];
    const int tid = threadIdx.x;
    const int m0 = blockIdx.x * 128;
    const int wave = tid >> 6;
    const int lane = tid & 63;
    const int l16 = lane & 15;
    const int quad = lane >> 4;
    const int wm = (wave & 1) * 64;
    const int wn = (wave >> 1) * 64;

    // ---- prologue: LN1 over shifted source rows ----
    {
        int row = tid >> 1;
        int half = (tid & 1) * 64;
        int gtok = win2tok(wid0 + m0 + row);
        const float* xp = x + (size_t)gtok * CC + half;
        float v[64];
        float s = 0.f, sq = 0.f;
        #pragma unroll
        for (int i = 0; i < 16; ++i) {
            float4 a = *(const float4*)(xp + i * 4);
            v[i * 4 + 0] = a.x; v[i * 4 + 1] = a.y;
            v[i * 4 + 2] = a.z; v[i * 4 + 3] = a.w;
            s += a.x + a.y + a.z + a.w;
            sq += a.x * a.x + a.y * a.y + a.z * a.z + a.w * a.w;
        }
        s += __shfl_xor(s, 1);
        sq += __shfl_xor(sq, 1);
        float mean = s * (1.0f / 128.0f);
        float var = sq * (1.0f / 128.0f) - mean * mean;
        float rstd = rsqrtf(var + 1e-5f);
        #pragma unroll
        for (int i = 0; i < 8; ++i) {
            ushort_t tmp[8];
            #pragma unroll
            for (int j = 0; j < 8; ++j) {
                int c = half + i * 8 + j;
                tmp[j] = f2bf((v[i * 8 + j] - mean) * rstd * g1[c] + b1[c]);
            }
            *(uint4*)&As[row * 136 + half + i * 8] = *(const uint4*)tmp;
        }
    }
    __syncthreads();

    // ---- 3 N-chunks of 128 cols ----
    for (int nc = 0; nc < 3; ++nc) {
        f32x4 acc[4][4];
        #pragma unroll
        for (int i = 0; i < 4; ++i)
            #pragma unroll
            for (int j = 0; j < 4; ++j)
                acc[i][j] = (f32x4){0.f, 0.f, 0.f, 0.f};
        #pragma unroll
        for (int kk = 0; kk < 128; kk += 32) {
            bf16x8 af[4], bfr[4];
            #pragma unroll
            for (int i = 0; i < 4; ++i)
                af[i] = *(const bf16x8*)&As[(wm + 16 * i + l16) * 136 + kk + quad * 8];
            #pragma unroll
            for (int j = 0; j < 4; ++j)
                bfr[j] = *(const bf16x8*)&wq[(size_t)(nc * 128 + wn + 16 * j + l16) * 128 + kk + quad * 8];
            #pragma unroll
            for (int i = 0; i < 4; ++i)
                #pragma unroll
                for (int j = 0; j < 4; ++j)
                    acc[i][j] = __builtin_amdgcn_mfma_f32_16x16x32_bf16(af[i], bfr[j], acc[i][j], 0, 0, 0);
        }
        #pragma unroll
        for (int j = 0; j < 4; ++j) {
            int col = nc * 128 + wn + 16 * j + l16;
            float bv = qkv_b[col];
            #pragma unroll
            for (int i = 0; i < 4; ++i)
                #pragma unroll
                for (int r = 0; r < 4; ++r) {
                    int row = m0 + wm + 16 * i + quad * 4 + r;
                    qkv[(size_t)row * 384 + col] = f2bf(acc[i][j][r] + bv);
                }
        }
    }
}

// ============ K2: MFMA windowed attention (verified r3/r4) ============
__global__ __launch_bounds__(256) void attn_mfma(
    const ushort_t* __restrict__ qkv, const float* __restrict__ bias,
    ushort_t* __restrict__ attn_out) {
    __shared__ __align__(16) ushort_t Vt[NHEAD][32 * 72];
    __shared__ __align__(16) ushort_t Ps[NHEAD][64 * 72];
    const int tid = threadIdx.x;
    const int wave = tid >> 6;
    const int lane = tid & 63;
    const int l16 = lane & 15;
    const int quad = lane >> 4;
    const int win = blockIdx.x;
    const int h = wave;
    const float scale = 0.17677669529663687f;

    ushort_t* vt = Vt[wave];
    ushort_t* ps = Ps[wave];

    {
        int r0 = lane >> 2;
        int dc = (lane & 3) * 8;
        #pragma unroll
        for (int pass = 0; pass < 4; ++pass) {
            int i = pass * 16 + r0;
            if (i < NN) {
                const ushort_t* src = &qkv[((size_t)(win * NN + i)) * 384 + 256 + h * HD + dc];
                ushort4 a = *(const ushort4*)src;
                ushort4 b = *(const ushort4*)(src + 4);
                vt[(dc + 0) * 72 + i] = a.x; vt[(dc + 1) * 72 + i] = a.y;
                vt[(dc + 2) * 72 + i] = a.z; vt[(dc + 3) * 72 + i] = a.w;
                vt[(dc + 4) * 72 + i] = b.x; vt[(dc + 5) * 72 + i] = b.y;
                vt[(dc + 6) * 72 + i] = b.z; vt[(dc + 7) * 72 + i] = b.w;
            }
        }
        #pragma unroll
        for (int j = 0; j < 8; ++j) {
            int idx = lane * 8 + j;
            if (idx < 32 * 15) {
                int d = idx / 15, n = NN + idx - d * 15;
                vt[d * 72 + n] = 0;
            }
        }
    }

    f32x4 s[4][4];
    {
        bf16x8 qa[4], kb[4];
        #pragma unroll
        for (int t = 0; t < 4; ++t) {
            size_t rb = ((size_t)(win * NN + 16 * t + l16)) * 384 + h * HD + quad * 8;
            qa[t] = *(const bf16x8*)&qkv[rb];
            kb[t] = *(const bf16x8*)&qkv[rb + 128];
        }
        #pragma unroll
        for (int mi = 0; mi < 4; ++mi)
            #pragma unroll
            for (int ni = 0; ni < 4; ++ni) {
                f32x4 z = {0.f, 0.f, 0.f, 0.f};
                s[mi][ni] = __builtin_amdgcn_mfma_f32_16x16x32_bf16(qa[mi], kb[ni], z, 0, 0, 0);
            }
    }

    const float* bh = bias + h * 4096;
    #pragma unroll
    for (int mi = 0; mi < 4; ++mi)
        #pragma unroll
        for (int ni = 0; ni < 4; ++ni)
            #pragma unroll
            for (int r = 0; r < 4; ++r)
                s[mi][ni][r] = s[mi][ni][r] * scale +
                               bh[(16 * mi + quad * 4 + r) * 64 + 16 * ni + l16];

    #pragma unroll
    for (int mi = 0; mi < 4; ++mi)
        #pragma unroll
        for (int r = 0; r < 4; ++r) {
            float m01 = fmaxf(s[mi][0][r], s[mi][1][r]);
            float m2 = s[mi][2][r];
            float m3 = (l16 == 0) ? s[mi][3][r] : -3.0e38f;
            float mx = fmaxf(fmaxf(m01, m2), m3);
            mx = fmaxf(mx, __shfl_xor(mx, 1));
            mx = fmaxf(mx, __shfl_xor(mx, 2));
            mx = fmaxf(mx, __shfl_xor(mx, 4));
            mx = fmaxf(mx, __shfl_xor(mx, 8));
            float e0 = expf(s[mi][0][r] - mx);
            float e1 = expf(s[mi][1][r] - mx);
            float e2 = expf(s[mi][2][r] - mx);
            float e3 = (l16 == 0) ? expf(s[mi][3][r] - mx) : 0.f;
            float sum = (e0 + e1) + (e2 + e3);
            sum += __shfl_xor(sum, 1);
            sum += __shfl_xor(sum, 2);
            sum += __shfl_xor(sum, 4);
            sum += __shfl_xor(sum, 8);
            float inv = 1.0f / sum;
            s[mi][0][r] = e0 * inv;
            s[mi][1][r] = e1 * inv;
            s[mi][2][r] = e2 * inv;
            s[mi][3][r] = e3 * inv;
        }

    #pragma unroll
    for (int mi = 0; mi < 4; ++mi)
        #pragma unroll
        for (int ni = 0; ni < 4; ++ni)
            #pragma unroll
            for (int r = 0; r < 4; ++r)
                ps[(16 * mi + quad * 4 + r) * 72 + 16 * ni + l16] = f2bf(s[mi][ni][r]);

    f32x4 o[2][4];
    #pragma unroll
    for (int it = 0; it < 2; ++it)
        #pragma unroll
        for (int jt = 0; jt < 4; ++jt)
            o[it][jt] = (f32x4){0.f, 0.f, 0.f, 0.f};
    #pragma unroll
    for (int k0 = 0; k0 < 64; k0 += 32) {
        bf16x8 va[2], pb[4];
        #pragma unroll
        for (int it = 0; it < 2; ++it)
            va[it] = *(const bf16x8*)&vt[(16 * it + l16) * 72 + k0 + quad * 8];
        #pragma unroll
        for (int jt = 0; jt < 4; ++jt)
            pb[jt] = *(const bf16x8*)&ps[(16 * jt + l16) * 72 + k0 + quad * 8];
        #pragma unroll
        for (int it = 0; it < 2; ++it)
            #pragma unroll
            for (int jt = 0; jt < 4; ++jt)
                o[it][jt] = __builtin_amdgcn_mfma_f32_16x16x32_bf16(va[it], pb[jt], o[it][jt], 0, 0, 0);
    }

    #pragma unroll
    for (int jt = 0; jt < 4; ++jt) {
        int m = 16 * jt + l16;
        if (m < NN) {
            #pragma unroll
            for (int it = 0; it < 2; ++it) {
                ushort4 st;
                st.x = f2bf(o[it][jt][0]);
                st.y = f2bf(o[it][jt][1]);
                st.z = f2bf(o[it][jt][2]);
                st.w = f2bf(o[it][jt][3]);
                *(ushort4*)&attn_out[((size_t)(win * NN + m)) * CC + h * HD + 16 * it + quad * 4] = st;
            }
        }
    }
}

// ============ K3: fused proj GEMM + window-reverse + residual + LN2 ============
// Block = 64 windowed-token rows. proj = attn@Wp^T+b -> LDS; epilogue scatters
// x2 = x[gtok]+proj -> out (fp32) and h2 = LN2(x2) -> h2buf (bf16, global order).
__global__ __launch_bounds__(256) void proj_fused(
    const ushort_t* __restrict__ attn, const ushort_t* __restrict__ wp,
    const float* __restrict__ proj_b, const float* __restrict__ x,
    const float* __restrict__ g2, const float* __restrict__ b2,
    float* __restrict__ out, ushort_t* __restrict__ h2buf, int wid0) {
    __shared__ __align__(16) ushort_t As[64 * 136];
    __shared__ __align__(16) ushort_t PS[64 * 136];
    const int tid = threadIdx.x;
    const int m0 = blockIdx.x * 64;
    const int wave = tid >> 6;
    const int lane = tid & 63;
    const int l16 = lane & 15;
    const int quad = lane >> 4;
    const int wn = wave * 32;

    // stage attn rows
    #pragma unroll
    for (int u = tid; u < 1024; u += 256) {
        int row = u >> 4, ch = (u & 15) * 8;
        *(uint4*)&As[row * 136 + ch] = *(const uint4*)&attn[(size_t)(m0 + row) * CC + ch];
    }
    __syncthreads();

    f32x4 acc[4][2];
    #pragma unroll
    for (int i = 0; i < 4; ++i)
        #pragma unroll
        for (int j = 0; j < 2; ++j)
            acc[i][j] = (f32x4){0.f, 0.f, 0.f, 0.f};
    #pragma unroll
    for (int kk = 0; kk < 128; kk += 32) {
        bf16x8 af[4], bfr[2];
        #pragma unroll
        for (int i = 0; i < 4; ++i)
            af[i] = *(const bf16x8*)&As[(16 * i + l16) * 136 + kk + quad * 8];
        #pragma unroll
        for (int j = 0; j < 2; ++j)
            bfr[j] = *(const bf16x8*)&wp[(size_t)(wn + 16 * j + l16) * 128 + kk + quad * 8];
        #pragma unroll
        for (int i = 0; i < 4; ++i)
            #pragma unroll
            for (int j = 0; j < 2; ++j)
                acc[i][j] = __builtin_amdgcn_mfma_f32_16x16x32_bf16(af[i], bfr[j], acc[i][j], 0, 0, 0);
    }
    #pragma unroll
    for (int j = 0; j < 2; ++j) {
        float bv = proj_b[wn + 16 * j + l16];
        #pragma unroll
        for (int i = 0; i < 4; ++i)
            #pragma unroll
            for (int r = 0; r < 4; ++r)
                PS[(16 * i + quad * 4 + r) * 136 + wn + 16 * j + l16] = f2bf(acc[i][j][r] + bv);
    }
    __syncthreads();

    // epilogue: 4 threads per row, 32 ch each
    {
        int row = tid >> 2;
        int ch0 = (tid & 3) * 32;
        int gtok = win2tok(wid0 + m0 + row);
        const float* xp = x + (size_t)gtok * CC + ch0;
        float v[32];
        float s = 0.f, sq = 0.f;
        #pragma unroll
        for (int i = 0; i < 4; ++i) {
            float4 a0 = *(const float4*)(xp + i * 8);
            float4 a1 = *(const float4*)(xp + i * 8 + 4);
            ushort4 p0 = *(const ushort4*)&PS[row * 136 + ch0 + i * 8];
            ushort4 p1 = *(const ushort4*)&PS[row * 136 + ch0 + i * 8 + 4];
            v[i * 8 + 0] = a0.x + bf2f(p0.x); v[i * 8 + 1] = a0.y + bf2f(p0.y);
            v[i * 8 + 2] = a0.z + bf2f(p0.z); v[i * 8 + 3] = a0.w + bf2f(p0.w);
            v[i * 8 + 4] = a1.x + bf2f(p1.x); v[i * 8 + 5] = a1.y + bf2f(p1.y);
            v[i * 8 + 6] = a1.z + bf2f(p1.z); v[i * 8 + 7] = a1.w + bf2f(p1.w);
            #pragma unroll
            for (int j = 0; j < 8; ++j) { s += v[i * 8 + j]; sq += v[i * 8 + j] * v[i * 8 + j]; }
        }
        float* op = out + (size_t)gtok * CC + ch0;
        #pragma unroll
        for (int i = 0; i < 8; ++i)
            *(float4*)(op + i * 4) = *(const float4*)(v + i * 4);
        s += __shfl_xor(s, 1);  sq += __shfl_xor(sq, 1);
        s += __shfl_xor(s, 2);  sq += __shfl_xor(sq, 2);
        float mean = s * (1.0f / 128.0f);
        float var = sq * (1.0f / 128.0f) - mean * mean;
        float rstd = rsqrtf(var + 1e-5f);
        #pragma unroll
        for (int i = 0; i < 4; ++i) {
            ushort_t tmp[8];
            #pragma unroll
            for (int j = 0; j < 8; ++j) {
                int c = ch0 + i * 8 + j;
                tmp[j] = f2bf((v[i * 8 + j] - mean) * rstd * g2[c] + b2[c]);
            }
            *(uint4*)&h2buf[(size_t)gtok * CC + ch0 + i * 8] = *(const uint4*)tmp;
        }
    }
}

// ============ K4: fused fc1+GELU+fc2 with RMW residual into d_out ============
// Block = 64 token rows (global order). 4 fc1 chunks of 128.
__global__ __launch_bounds__(256) void mlp2(
    const ushort_t* __restrict__ h2, const ushort_t* __restrict__ w1,
    const float* __restrict__ b1, const ushort_t* __restrict__ w2,
    const float* __restrict__ bias2, float* __restrict__ out) {
    __shared__ __align__(16) ushort_t H2[64 * 136];
    __shared__ __align__(16) ushort_t PS[64 * 136];
    const int tid = threadIdx.x;
    const int m0 = blockIdx.x * 64;
    const int wave = tid >> 6;
    const int lane = tid & 63;
    const int l16 = lane & 15;
    const int quad = lane >> 4;
    const int wn = wave * 32;

    #pragma unroll
    for (int u = tid; u < 1024; u += 256) {
        int row = u >> 4, ch = (u & 15) * 8;
        *(uint4*)&H2[row * 136 + ch] = *(const uint4*)&h2[(size_t)(m0 + row) * CC + ch];
    }
    __syncthreads();

    f32x4 acc[4][2];
    #pragma unroll
    for (int i = 0; i < 4; ++i)
        #pragma unroll
        for (int j = 0; j < 2; ++j)
            acc[i][j] = (f32x4){0.f, 0.f, 0.f, 0.f};

    for (int c = 0; c < 4; ++c) {
        // MFMA1: P = H2 @ W1c^T  (64 x 128)
        f32x4 s1[4][2];
        #pragma unroll
        for (int i = 0; i < 4; ++i)
            #pragma unroll
            for (int j = 0; j < 2; ++j)
                s1[i][j] = (f32x4){0.f, 0.f, 0.f, 0.f};
        #pragma unroll
        for (int kk = 0; kk < 128; kk += 32) {
            bf16x8 af[4], bfr[2];
            #pragma unroll
            for (int i = 0; i < 4; ++i)
                af[i] = *(const bf16x8*)&H2[(16 * i + l16) * 136 + kk + quad * 8];
            #pragma unroll
            for (int j = 0; j < 2; ++j)
                bfr[j] = *(const bf16x8*)&w1[(size_t)(c * 128 + wn + 16 * j + l16) * 128 + kk + quad * 8];
            #pragma unroll
            for (int i = 0; i < 4; ++i)
                #pragma unroll
                for (int j = 0; j < 2; ++j)
                    s1[i][j] = __builtin_amdgcn_mfma_f32_16x16x32_bf16(af[i], bfr[j], s1[i][j], 0, 0, 0);
        }
        // bias + GELU
        #pragma unroll
        for (int j = 0; j < 2; ++j) {
            float bv = b1[c * 128 + wn + 16 * j + l16];
            #pragma unroll
            for (int i = 0; i < 4; ++i)
                #pragma unroll
                for (int r = 0; r < 4; ++r) {
                    float u = s1[i][j][r] + bv;
                    float z = 1.5957691216f * u * (1.0f + 0.044715f * u * u);
                    s1[i][j][r] = u / (1.0f + __expf(-z));
                }
        }
        __syncthreads();   // previous chunk's MFMA2 done with PS
        #pragma unroll
        for (int i = 0; i < 4; ++i)
            #pragma unroll
            for (int j = 0; j < 2; ++j)
                #pragma unroll
                for (int r = 0; r < 4; ++r)
                    PS[(16 * i + quad * 4 + r) * 136 + wn + 16 * j + l16] = f2bf(s1[i][j][r]);
        __syncthreads();
        // MFMA2: acc += P @ W2c^T
        #pragma unroll
        for (int kk = 0; kk < 128; kk += 32) {
            bf16x8 af[4], bfr[2];
            #pragma unroll
            for (int i = 0; i < 4; ++i)
                af[i] = *(const bf16x8*)&PS[(16 * i + l16) * 136 + kk + quad * 8];
            #pragma unroll
            for (int j = 0; j < 2; ++j)
                bfr[j] = *(const bf16x8*)&w2[(size_t)(wn + 16 * j + l16) * 512 + c * 128 + kk + quad * 8];
            #pragma unroll
            for (int i = 0; i < 4; ++i)
                #pragma unroll
                for (int j = 0; j < 2; ++j)
                    acc[i][j] = __builtin_amdgcn_mfma_f32_16x16x32_bf16(af[i], bfr[j], acc[i][j], 0, 0, 0);
        }
    }

    #pragma unroll
    for (int j = 0; j < 2; ++j) {
        int col = wn + 16 * j + l16;
        float bv = bias2[col];
        #pragma unroll
        for (int i = 0; i < 4; ++i)
            #pragma unroll
            for (int r = 0; r < 4; ++r) {
                size_t oi = (size_t)(m0 + 16 * i + quad * 4 + r) * CC + col;
                out[oi] += acc[i][j][r] + bv;
            }
    }
}

// ============ launch ============
extern "C" void kernel_launch(void* const* d_in, const int* in_sizes, int n_in,
                              void* d_out, int out_size, void* d_ws, size_t ws_size,
                              hipStream_t stream) {
    const float* x       = (const float*)d_in[0];
    const float* norm1_g = (const float*)d_in[1];
    const float* norm1_b = (const float*)d_in[2];
    const float* qkv_w   = (const float*)d_in[3];
    const float* qkv_b   = (const float*)d_in[4];
    const float* rpb     = (const float*)d_in[5];
    const float* proj_w  = (const float*)d_in[6];
    const float* proj_b  = (const float*)d_in[7];
    const float* norm2_g = (const float*)d_in[8];
    const float* norm2_b = (const float*)d_in[9];
    const float* fc1_w   = (const float*)d_in[10];
    const float* fc1_b   = (const float*)d_in[11];
    const float* fc2_w   = (const float*)d_in[12];
    const float* fc2_b   = (const float*)d_in[13];
    const int*   rel_idx = (const int*)d_in[14];

    char* ws = (char*)d_ws;
    float*    biasT = (float*)ws;
    ushort_t* wall  = (ushort_t*)(ws + 65536);
    ushort_t* wqkv  = wall;
    ushort_t* wproj = wall + 49152;
    ushort_t* wfc1  = wall + 65536;
    ushort_t* wfc2  = wall + 131072;
    const size_t base = 524288;
    const size_t szH = (size_t)NTOK * CC * 2;        // 25.7 MB (h2)
    int f = 1;
    while (f < 16) {
        size_t szQ = (size_t)NTOK * 384 * 2 / f;
        size_t szA = (size_t)NTOK * CC * 2 / f;
        if (base + szQ + szA + szH <= ws_size) break;
        f *= 2;
    }
    const size_t szQ = (size_t)NTOK * 384 * 2 / f;
    const size_t szA = (size_t)NTOK * CC * 2 / f;
    int Mc = NTOK / f;
    int wc = NWIN / f;

    ushort_t* Qreg = (ushort_t*)(ws + base);               // qkv chunk
    ushort_t* Areg = (ushort_t*)(ws + base + szQ);          // attn out chunk
    ushort_t* h2buf = (ushort_t*)(ws + base + szQ + szA);   // full h2

    prep_weights<<<dim3(768), dim3(256), 0, stream>>>(qkv_w, proj_w, fc1_w, fc2_w, wall);
    build_bias<<<dim3(NHEAD), dim3(256), 0, stream>>>(rpb, rel_idx, biasT);
    for (int c = 0; c < f; ++c) {
        qkv_fused<<<dim3(Mc / 128), dim3(256), 0, stream>>>(
            x, norm1_g, norm1_b, wqkv, qkv_b, Qreg, c * Mc);
        attn_mfma<<<dim3(wc), dim3(256), 0, stream>>>(Qreg, biasT, Areg);
        proj_fused<<<dim3(Mc / 64), dim3(256), 0, stream>>>(
            Areg, wproj, proj_b, x, norm2_g, norm2_b, (float*)d_out, h2buf, c * Mc);
    }
    mlp2<<<dim3(NTOK / 64), dim3(256), 0, stream>>>(
        h2buf, wfc1, fc1_b, wfc2, fc2_b, (float*)d_out);
}